// Round 1
// 105.361 us; speedup vs baseline: 1.2165x; 1.2165x over previous
//
#include <hip/hip_runtime.h>
#include <math.h>

// B=2, HD=4, H=W=128, KSIZE=7 (K=49), NSP=9, S=64
#define BN   2
#define HDN  4
#define HN   128
#define WN   128
#define KS   7
#define KK   49
#define NSPN 9
#define SN   64
#define PPB  32      // pixels per block
#define TPB  128     // threads per block (32 pix x 4 heads)
#define PROW 52      // padded LDS row stride (floats), 16B-aligned

// v3: T14 async-stage split everywhere. All global->LDS paths are now
// issue-loads-to-registers-early / ds_write-late, so the 16 gather loads per
// sp-plane are batched in flight (MLP ~150 lines/wave instead of ~2) and
// their latency hides under the current plane's compute. attn/out accessed
// as dwordx4 (dword-aligned multi-dword loads are legal on gfx950).
__global__ __launch_bounds__(TPB, 2) void attn_rw3(
    const float* __restrict__ attn,
    const float* __restrict__ sims,
    const int*   __restrict__ sinds,
    float*       __restrict__ out)
{
    __shared__ __align__(16) float pbuf[2][PPB * PROW];
    __shared__ int   g_lds[PPB * NSPN];
    __shared__ float pi_lds[PPB * NSPN];

    const int t    = threadIdx.x;
    const int lane = t & 63;
    const int wv   = t >> 6;                 // wave id 0..1
    const int bx   = blockIdx.x;
    const int wseg = bx & 3;
    const int hh   = (bx >> 2) & 127;
    const int b    = bx >> 9;
    const int ww0  = wseg * PPB;

    const int pix_c = t & 31;                // compute mapping
    const int hd    = t >> 5;

    const float* simsB = sims + ((size_t)b << 20);   // b * 64*128*128
    int hs = hh - 3; hs = max(0, min(HN - KS, hs));  // uniform per block

    // ---- Phase 0: batched attn loads (dwordx4) + reg-staged sinds ----
    float a[KK];
    {
        const size_t abase =
            ((((size_t)b * HDN + hd) * HN + hh) * WN + (ww0 + pix_c)) * (size_t)KK;
        const float* ap = attn + abase;
        #pragma unroll
        for (int j = 0; j < 12; ++j)
            __builtin_memcpy(&a[4 * j], ap + 4 * j, 16);   // global_load_dwordx4, align 4
        a[48] = ap[48];
    }
    const int sbase = ((b * HN + hh) * WN + ww0) * NSPN;
    {
        // 288 ints: loads first (batched), LDS writes after
        int s0 = sinds[sbase + t];
        int s1 = sinds[sbase + t + 128];
        int s2 = (t < 32) ? sinds[sbase + t + 256] : 0;
        g_lds[t] = s0;
        g_lds[t + 128] = s1;
        if (t < 32) g_lds[t + 256] = s2;
    }
    __syncthreads();

    // gather lane constants
    const int  gki  = lane / KS;
    const int  gkj  = lane - gki * KS;
    const bool gact = lane < KK;
    const int  laneoff = gact ? (gki * WN + gkj) : 0;   // clamped: lanes 49..63 stay in-bounds

    // register-staged gather: issue 16 loads -> gr[], ds_write later
    float gr[16];
    auto gather_load = [&](int gv) {
        #pragma unroll
        for (int i = 0; i < 16; ++i) {
            int g   = __builtin_amdgcn_readlane(gv, i);   // scalar g
            int pix = wv * 16 + i;
            int ws  = ww0 + pix - 3; ws = max(0, min(WN - KS, ws));
            gr[i] = simsB[(g << 14) + hs * WN + ws + laneoff];
        }
    };
    auto gather_store = [&](int buf) {
        if (gact) {
            #pragma unroll
            for (int i = 0; i < 16; ++i)
                pbuf[buf][(wv * 16 + i) * PROW + lane] = gr[i];
        }
    };

    // ---- Phase 1: issue gather(0) + pi loads, softmax under their latency ----
    int gv0 = 0;
    if (lane < 16) gv0 = g_lds[(wv * 16 + lane) * NSPN];
    int pg0 = g_lds[t];
    int pg1 = g_lds[t + 128];
    int pg2 = (t < 32) ? g_lds[t + 256] : 0;

    gather_load(gv0);                                   // 16 loads in flight

    float pv0 = simsB[(pg0 << 14) + hh * WN + ww0 + (t / NSPN)];
    float pv1 = simsB[(pg1 << 14) + hh * WN + ww0 + ((t + 128) / NSPN)];
    float pv2 = 0.0f;
    if (t < 32) pv2 = simsB[(pg2 << 14) + hh * WN + ww0 + ((t + 256) / NSPN)];

    // softmax on a[] (pure VALU, overlaps outstanding global loads)
    {
        float m0 = a[0], m1 = a[1], m2 = a[2], m3 = a[3];
        #pragma unroll
        for (int k = 4; k < KK; k += 4) {
            m0 = fmaxf(m0, a[k]);
            if (k + 1 < KK) m1 = fmaxf(m1, a[k + 1]);
            if (k + 2 < KK) m2 = fmaxf(m2, a[k + 2]);
            if (k + 3 < KK) m3 = fmaxf(m3, a[k + 3]);
        }
        float m = fmaxf(fmaxf(m0, m1), fmaxf(m2, m3));
        #pragma unroll
        for (int k = 0; k < KK; ++k) a[k] = __expf(a[k] - m);
    }

    pi_lds[t] = pv0;
    pi_lds[t + 128] = pv1;
    if (t < 32) pi_lds[t + 256] = pv2;
    gather_store(0);
    __syncthreads();     // pbuf[0], pi_lds ready

    float acc[KK];
    #pragma unroll
    for (int k = 0; k < KK; ++k) acc[k] = 0.0f;

    for (int sp = 0; sp < NSPN; ++sp) {
        const int buf  = sp & 1;
        const bool more = (sp + 1 < NSPN);

        // issue next plane's 16 loads BEFORE compute (latency hides under it)
        int gv = 0;
        if (more && lane < 16)
            gv = g_lds[(wv * 16 + lane) * NSPN + sp + 1];
        if (more) gather_load(gv);

        float pi = pi_lds[pix_c * NSPN + sp];

        // load p row into regs (12 x b128 + 1)
        float p[KK];
        const float* prow = &pbuf[buf][pix_c * PROW];
        #pragma unroll
        for (int k4 = 0; k4 < 12; ++k4) {
            float4 v = *(const float4*)(prow + k4 * 4);
            p[k4 * 4 + 0] = v.x; p[k4 * 4 + 1] = v.y;
            p[k4 * 4 + 2] = v.z; p[k4 * 4 + 3] = v.w;
        }
        p[48] = prow[48];

        // denom: 4-way split FMA chains
        float d0 = 0.f, d1 = 0.f, d2 = 0.f, d3 = 0.f;
        #pragma unroll
        for (int k = 0; k < 48; k += 4) {
            d0 = fmaf(a[k + 0], p[k + 0], d0);
            d1 = fmaf(a[k + 1], p[k + 1], d1);
            d2 = fmaf(a[k + 2], p[k + 2], d2);
            d3 = fmaf(a[k + 3], p[k + 3], d3);
        }
        d0 = fmaf(a[48], p[48], d0);
        float d  = (d0 + d1) + (d2 + d3);

        float coef = pi * __builtin_amdgcn_rcpf(d + 1e-10f);

        #pragma unroll
        for (int k = 0; k < KK; ++k) acc[k] = fmaf(coef, p[k], acc[k]);

        // write next plane to LDS only now (loads have had compute-time to land)
        if (more) {
            gather_store(buf ^ 1);
            __syncthreads();   // publish pbuf[buf^1]; WAR-protect buf
        }
    }

    // ---- epilogue: out[k] = a[k] * acc[k], dwordx4 stores ----
    const size_t obase =
        ((((size_t)b * HDN + hd) * HN + hh) * WN + (ww0 + pix_c)) * (size_t)KK;
    #pragma unroll
    for (int k = 0; k < KK; ++k) a[k] *= acc[k];
    float* op = out + obase;
    #pragma unroll
    for (int j = 0; j < 12; ++j)
        __builtin_memcpy(op + 4 * j, &a[4 * j], 16);   // global_store_dwordx4, align 4
    op[48] = a[48];
}

extern "C" void kernel_launch(void* const* d_in, const int* in_sizes, int n_in,
                              void* d_out, int out_size, void* d_ws, size_t ws_size,
                              hipStream_t stream) {
    const float* attn  = (const float*)d_in[0];
    const float* sims  = (const float*)d_in[1];
    const int*   sinds = (const int*)d_in[2];
    float*       outp  = (float*)d_out;

    // blocks: b(2) x hh(128) x wseg(4) = 1024
    const int blocks = BN * HN * (WN / PPB);
    attn_rw3<<<blocks, TPB, 0, stream>>>(attn, sims, sinds, outp);
}